// Round 6
// baseline (527.875 us; speedup 1.0000x reference)
//
#include <hip/hip_runtime.h>
#include <math.h>

#define NN 20000
#define EE 320000

// scales
#define INV_UV    0.04419417382415922f   // 1/sqrt(64*8)
#define INV_MULS  0.125f                 // 1/sqrt(64)
#define S_BASIS   0.35355339059327373f   // 1/sqrt(8)
#define S_HID     0.125f                 // 1/sqrt(64)
#define INV_SQ3   0.5773502691896258f
#define AGG_SCALE (0.25f * 0.08838834764831845f)  // inv_nn * inv_mid

typedef __attribute__((ext_vector_type(8))) short bf16x8;
typedef __attribute__((ext_vector_type(4))) float f32x4;

__device__ __forceinline__ float sspf(float x) {
  return fmaxf(x, 0.0f) + __logf(1.0f + __expf(-fabsf(x))) - 0.69314718055994531f;
}

__device__ __forceinline__ short f2bf(float f) {
  unsigned u = __float_as_uint(f);
  u += 0x7fffu + ((u >> 16) & 1u);       // round-to-nearest-even
  return (short)(u >> 16);
}

// ---------------------------------------------------------------------------
// CSR build: histogram -> single-block scan -> scatter+pack (eord records)
// eord record (16 dwords): [0..7]=basis, [8..11]=sh, [12]=src, [13]=dst
// ---------------------------------------------------------------------------
__global__ __launch_bounds__(256) void k_hist(const int* __restrict__ edge_idx,
                                              int* __restrict__ deg) {
  int e = blockIdx.x * 256 + threadIdx.x;
  atomicAdd(&deg[edge_idx[2 * (size_t)e]], 1);
}

__global__ __launch_bounds__(1024) void k_scan(const int* __restrict__ deg,
                                               int* __restrict__ cursor) {
  __shared__ int part[1024];
  const int t = threadIdx.x;
  const int base = t * 20;
  int loc[20];
  int run = 0;
  #pragma unroll
  for (int i = 0; i < 20; ++i) {
    int idx = base + i;
    int v = (idx < NN) ? deg[idx] : 0;
    loc[i] = run; run += v;
  }
  part[t] = run;
  __syncthreads();
  for (int off = 1; off < 1024; off <<= 1) {
    int v = (t >= off) ? part[t - off] : 0;
    __syncthreads();
    part[t] += v;
    __syncthreads();
  }
  int ex = (t > 0) ? part[t - 1] : 0;
  #pragma unroll
  for (int i = 0; i < 20; ++i) {
    int idx = base + i;
    if (idx < NN) cursor[idx] = ex + loc[i];
  }
}

__global__ __launch_bounds__(256) void k_scatter_pack(
    const float* __restrict__ edge_basis, const float* __restrict__ edge_sh,
    const int* __restrict__ edge_idx, int* __restrict__ cursor,
    float* __restrict__ eord) {
  int e = blockIdx.x * 256 + threadIdx.x;
  int2 di = *(const int2*)(edge_idx + 2 * (size_t)e);
  int pos = atomicAdd(&cursor[di.x], 1);
  float4 b0 = *(const float4*)(edge_basis + (size_t)e * 8);
  float4 b1 = *(const float4*)(edge_basis + (size_t)e * 8 + 4);
  float4 s4 = *(const float4*)(edge_sh + (size_t)e * 4);
  float* r = eord + (size_t)pos * 16;
  *(float4*)(r)     = b0;
  *(float4*)(r + 4) = b1;
  *(float4*)(r + 8) = s4;
  r[12] = __int_as_float(di.y);   // src
  r[13] = __int_as_float(di.x);   // dst
}

// Wfc2 -> bf16 B-fragment order (S_HID folded). Thread t of k2 reads
// wfc2b[t*64 + (ks*4+nt)*8 + j].
__global__ __launch_bounds__(256) void k_wprep(const float* __restrict__ Wfc2,
                                               unsigned short* __restrict__ wfc2b) {
  int fi = blockIdx.x * 256 + threadIdx.x;   // grid 64 -> 16384
  int tt = fi >> 6;
  int ks = (fi >> 5) & 1;
  int nt = (fi >> 3) & 3;
  int j  = fi & 7;
  int lane = tt & 63, wvv = tt >> 6;
  int row = ks * 32 + (lane >> 4) * 8 + j;
  int col = wvv * 64 + nt * 16 + (lane & 15);
  wfc2b[fi] = (unsigned short)f2bf(Wfc2[(size_t)row * 256 + col] * S_HID);
}

// ---------------------------------------------------------------------------
// K1: per-node prep (unchanged; ~76% of fp32 peak).
// ---------------------------------------------------------------------------
__global__ __launch_bounds__(256) void k1_node_prep(
    const float* __restrict__ node_feat, const float* __restrict__ node_attr,
    const float* __restrict__ W1s, const float* __restrict__ W1v,
    const float* __restrict__ Wsc_s, const float* __restrict__ Wsc_v,
    float* __restrict__ out_, float* __restrict__ ws_s, float* __restrict__ ws_v)
{
  __shared__ float s0T[64][33];
  __shared__ float v0T[3][64][33];
  __shared__ float attrT[8][33];
  __shared__ float XT[64][36];
  __shared__ float Wl[64][68];

  const int t = threadIdx.x;
  const int n0 = blockIdx.x * 32;

  #pragma unroll
  for (int i = 0; i < 32; ++i) {
    int idx = t + i * 256;
    int n = idx >> 8, j = idx & 255;
    float val = node_feat[(size_t)(n0 + n) * 256 + j];
    if (j < 64) s0T[j][n] = val;
    else { int r = j - 64; v0T[r % 3][r / 3][n] = val; }
  }
  {
    int n = t >> 3, v = t & 7;
    attrT[v][n] = node_attr[(size_t)(n0 + n) * 8 + v];
  }
  __syncthreads();

  const int tn = t >> 4;
  const int tw = t & 15;

  for (int ch = 0; ch < 4; ++ch) {
    const float (*S)[33] = (ch == 0) ? s0T : v0T[ch - 1];
    const float* Wg = (ch == 0) ? Wsc_s : Wsc_v;
    float acc[2][4] = {{0.f,0.f,0.f,0.f},{0.f,0.f,0.f,0.f}};
    for (int kc = 0; kc < 8; ++kc) {
      #pragma unroll
      for (int i = 0; i < 8; ++i) {
        int idx = t + i * 256;
        int kk = idx >> 5, n = idx & 31;
        XT[kk][n] = S[kc * 8 + (kk >> 3)][n] * attrT[kk & 7][n];
      }
      #pragma unroll
      for (int i = 0; i < 16; ++i) {
        int idx = t + i * 256;
        int kk = idx >> 6, w = idx & 63;
        Wl[kk][w] = Wg[(size_t)(kc * 64 + kk) * 64 + w];
      }
      __syncthreads();
      #pragma unroll 8
      for (int kk = 0; kk < 64; ++kk) {
        float a0 = XT[kk][tn * 2 + 0];
        float a1 = XT[kk][tn * 2 + 1];
        float b0 = Wl[kk][tw * 4 + 0];
        float b1 = Wl[kk][tw * 4 + 1];
        float b2 = Wl[kk][tw * 4 + 2];
        float b3 = Wl[kk][tw * 4 + 3];
        acc[0][0] = fmaf(a0, b0, acc[0][0]);
        acc[0][1] = fmaf(a0, b1, acc[0][1]);
        acc[0][2] = fmaf(a0, b2, acc[0][2]);
        acc[0][3] = fmaf(a0, b3, acc[0][3]);
        acc[1][0] = fmaf(a1, b0, acc[1][0]);
        acc[1][1] = fmaf(a1, b1, acc[1][1]);
        acc[1][2] = fmaf(a1, b2, acc[1][2]);
        acc[1][3] = fmaf(a1, b3, acc[1][3]);
      }
      __syncthreads();
    }
    #pragma unroll
    for (int i = 0; i < 2; ++i) {
      int n = n0 + tn * 2 + i;
      #pragma unroll
      for (int j = 0; j < 4; ++j) {
        int w = tw * 4 + j;
        float val = acc[i][j] * INV_UV;
        if (ch == 0) out_[(size_t)n * 256 + w] = val;
        else         out_[(size_t)n * 256 + 64 + w * 3 + (ch - 1)] = val;
      }
    }
  }

  {
    #pragma unroll
    for (int i = 0; i < 16; ++i) {
      int idx = t + i * 256;
      Wl[idx >> 6][idx & 63] = W1s[idx];
    }
    __syncthreads();
    float acc[2][4] = {{0.f,0.f,0.f,0.f},{0.f,0.f,0.f,0.f}};
    #pragma unroll 8
    for (int kk = 0; kk < 64; ++kk) {
      float a0 = s0T[kk][tn * 2 + 0];
      float a1 = s0T[kk][tn * 2 + 1];
      float b0 = Wl[kk][tw * 4 + 0];
      float b1 = Wl[kk][tw * 4 + 1];
      float b2 = Wl[kk][tw * 4 + 2];
      float b3 = Wl[kk][tw * 4 + 3];
      acc[0][0] = fmaf(a0, b0, acc[0][0]);
      acc[0][1] = fmaf(a0, b1, acc[0][1]);
      acc[0][2] = fmaf(a0, b2, acc[0][2]);
      acc[0][3] = fmaf(a0, b3, acc[0][3]);
      acc[1][0] = fmaf(a1, b0, acc[1][0]);
      acc[1][1] = fmaf(a1, b1, acc[1][1]);
      acc[1][2] = fmaf(a1, b2, acc[1][2]);
      acc[1][3] = fmaf(a1, b3, acc[1][3]);
    }
    #pragma unroll
    for (int i = 0; i < 2; ++i) {
      int n = n0 + tn * 2 + i;
      #pragma unroll
      for (int j = 0; j < 4; ++j)
        ws_s[(size_t)n * 64 + tw * 4 + j] = acc[i][j] * INV_MULS;
    }
    __syncthreads();
    #pragma unroll
    for (int i = 0; i < 16; ++i) {
      int idx = t + i * 256;
      Wl[idx >> 6][idx & 63] = W1v[idx];
    }
    __syncthreads();
    #pragma unroll 1
    for (int c = 0; c < 3; ++c) {
      float acc2[2][4] = {{0.f,0.f,0.f,0.f},{0.f,0.f,0.f,0.f}};
      #pragma unroll 8
      for (int kk = 0; kk < 64; ++kk) {
        float a0 = v0T[c][kk][tn * 2 + 0];
        float a1 = v0T[c][kk][tn * 2 + 1];
        float b0 = Wl[kk][tw * 4 + 0];
        float b1 = Wl[kk][tw * 4 + 1];
        float b2 = Wl[kk][tw * 4 + 2];
        float b3 = Wl[kk][tw * 4 + 3];
        acc2[0][0] = fmaf(a0, b0, acc2[0][0]);
        acc2[0][1] = fmaf(a0, b1, acc2[0][1]);
        acc2[0][2] = fmaf(a0, b2, acc2[0][2]);
        acc2[0][3] = fmaf(a0, b3, acc2[0][3]);
        acc2[1][0] = fmaf(a1, b0, acc2[1][0]);
        acc2[1][1] = fmaf(a1, b1, acc2[1][1]);
        acc2[1][2] = fmaf(a1, b2, acc2[1][2]);
        acc2[1][3] = fmaf(a1, b3, acc2[1][3]);
      }
      #pragma unroll
      for (int i = 0; i < 2; ++i) {
        int n = n0 + tn * 2 + i;
        #pragma unroll
        for (int j = 0; j < 4; ++j)
          ws_v[((size_t)n * 3 + c) * 64 + tw * 4 + j] = acc2[i][j] * INV_MULS;
      }
    }
  }
}

// ---------------------------------------------------------------------------
// K2 v3: 64 dst-sorted edges / block, 4 waves, coalesced eord front-end,
//   preconverted bf16 Wfc2 fragments, MFMA MLP2, chunked-pipelined gathers,
//   register TP accumulate with atomic flush on dst change.
// ---------------------------------------------------------------------------
__global__ __launch_bounds__(256) void k2_edge_csr(
    const float* __restrict__ eord, const float* __restrict__ Wfc1,
    const unsigned short* __restrict__ wfc2b,
    const float* __restrict__ ws_s, const float* __restrict__ ws_v,
    float* __restrict__ aggS, float* __restrict__ aggV)
{
  __shared__ float stageL[64][16];   // [e][0..7 basis | 8..11 sh | 12 src | 13 dst]
  __shared__ float wfc1[8][64];
  __shared__ short Hlb[64 * 64];     // bf16 H, XOR-swizzled rows (8 KB)
  __shared__ float Wt[64][258];      // stride 258: 2-way bank aliasing (free)

  const int t = threadIdx.x;
  const int e0 = blockIdx.x * 64;
  const int wv = t >> 6, lane = t & 63;

  // ---- coalesced stage: 64 records x 64B = one float4 per thread ----
  {
    float4 r = *(const float4*)(eord + (size_t)e0 * 16 + t * 4);
    *(float4*)&stageL[t >> 2][(t & 3) * 4] = r;
  }
  #pragma unroll
  for (int i = 0; i < 2; ++i) {
    int idx = t + i * 256;
    wfc1[idx >> 6][idx & 63] = Wfc1[idx] * S_BASIS;
  }
  // ---- B fragments: preconverted bf16, 8 x 16B contiguous loads ----
  bf16x8 bfrag[2][4];
  {
    const bf16x8* p = (const bf16x8*)(wfc2b + (size_t)t * 64);
    #pragma unroll
    for (int ks = 0; ks < 2; ++ks)
      #pragma unroll
      for (int nt = 0; nt < 4; ++nt)
        bfrag[ks][nt] = p[ks * 4 + nt];
  }
  __syncthreads();   // stageL, wfc1 visible

  // ---- preload gather chunk 0 (edges 0..15); flies through H + MFMA ----
  float gA[16], gB[16], gC[16];
  #pragma unroll
  for (int i = 0; i < 16; ++i) {
    int s = __float_as_int(stageL[i][12]);
    if (wv <= 1) gA[i] = ws_s[(size_t)s * 64 + lane];
    else {
      const float* p = ws_v + (size_t)s * 192 + lane;
      gA[i] = p[0]; gB[i] = p[64]; gC[i] = p[128];
    }
  }

  // ---- H = ssp(basis @ wfc1) -> bf16 pairs, swizzled LDS ----
  #pragma unroll
  for (int i = 0; i < 8; ++i) {
    int idx = t + i * 256;
    int e = idx >> 5, j2 = idx & 31;
    float a0 = 0.f, a1 = 0.f;
    #pragma unroll
    for (int b = 0; b < 8; ++b) {
      float bs = stageL[e][b];
      a0 = fmaf(bs, wfc1[b][2 * j2 + 0], a0);
      a1 = fmaf(bs, wfc1[b][2 * j2 + 1], a1);
    }
    unsigned pck = ((unsigned)(unsigned short)f2bf(sspf(a0))) |
                   (((unsigned)(unsigned short)f2bf(sspf(a1))) << 16);
    int byte_off = e * 128 + ((j2 * 4) ^ ((e & 7) << 4));
    *(unsigned*)((char*)Hlb + byte_off) = pck;
  }
  __syncthreads();

  // ---- MFMA: Wt = H @ Wfc2 (wave wv -> cols wv*64..wv*64+63) ----
  {
    const int er = lane & 15;
    const int kr = (lane >> 4) * 8;
    #pragma unroll
    for (int mt = 0; mt < 4; ++mt) {
      int e = mt * 16 + er;
      bf16x8 af0 = *(const bf16x8*)((const char*)Hlb + e * 128 + ((kr * 2)        ^ ((e & 7) << 4)));
      bf16x8 af1 = *(const bf16x8*)((const char*)Hlb + e * 128 + (((32 + kr) * 2) ^ ((e & 7) << 4)));
      #pragma unroll
      for (int nt = 0; nt < 4; ++nt) {
        f32x4 acc = {0.f, 0.f, 0.f, 0.f};
        acc = __builtin_amdgcn_mfma_f32_16x16x32_bf16(af0, bfrag[0][nt], acc, 0, 0, 0);
        acc = __builtin_amdgcn_mfma_f32_16x16x32_bf16(af1, bfrag[1][nt], acc, 0, 0, 0);
        int row = mt * 16 + (lane >> 4) * 4;
        int col = wv * 64 + nt * 16 + (lane & 15);
        #pragma unroll
        for (int r = 0; r < 4; ++r)
          Wt[row + r][col] = acc[r];
      }
    }
  }
  __syncthreads();

  // ---- TP: 4 chunks of 16, double-buffered gathers, flush on dst change ----
  const int part = wv;
  float acc0 = 0.f, acc1 = 0.f, acc2 = 0.f;
  int cur = __float_as_int(stageL[0][13]);

  auto flush = [&](int node) {
    size_t nb = (size_t)node;
    if (part == 0)      atomicAdd(&aggS[nb * 128 + lane], acc0);
    else if (part == 3) atomicAdd(&aggS[nb * 128 + 64 + lane], acc0);
    else if (part == 1) {
      atomicAdd(&aggV[nb * 384 +       lane], acc0);
      atomicAdd(&aggV[nb * 384 + 128 + lane], acc1);
      atomicAdd(&aggV[nb * 384 + 256 + lane], acc2);
    } else {
      atomicAdd(&aggV[nb * 384 +  64 + lane], acc0);
      atomicAdd(&aggV[nb * 384 + 192 + lane], acc1);
      atomicAdd(&aggV[nb * 384 + 320 + lane], acc2);
    }
  };

  if (part <= 1) {
    float hA[16];
    auto loadc = [&](float* bA, int c) {
      #pragma unroll
      for (int i = 0; i < 16; ++i) {
        int s = __float_as_int(stageL[c * 16 + i][12]);
        bA[i] = ws_s[(size_t)s * 64 + lane];
      }
    };
    auto proc = [&](const float* bA, int c) {
      #pragma unroll
      for (int i = 0; i < 16; ++i) {
        int e = c * 16 + i;
        int dstE = __float_as_int(stageL[e][13]);
        if (dstE != cur) { flush(cur); acc0 = acc1 = acc2 = 0.f; cur = dstE; }
        float w = Wt[e][part * 64 + lane];
        if (part == 0) {
          acc0 = fmaf(w * bA[i], stageL[e][8], acc0);
        } else {
          float wx = w * bA[i];
          acc0 = fmaf(wx, stageL[e][9],  acc0);
          acc1 = fmaf(wx, stageL[e][10], acc1);
          acc2 = fmaf(wx, stageL[e][11], acc2);
        }
      }
    };
    loadc(hA, 1);
    proc(gA, 0);
    loadc(gA, 2);
    proc(hA, 1);
    loadc(hA, 3);
    proc(gA, 2);
    proc(hA, 3);
  } else {
    float hA[16], hB[16], hC[16];
    auto loadc = [&](float* bA, float* bB, float* bC, int c) {
      #pragma unroll
      for (int i = 0; i < 16; ++i) {
        int s = __float_as_int(stageL[c * 16 + i][12]);
        const float* p = ws_v + (size_t)s * 192 + lane;
        bA[i] = p[0]; bB[i] = p[64]; bC[i] = p[128];
      }
    };
    auto proc = [&](const float* bA, const float* bB, const float* bC, int c) {
      #pragma unroll
      for (int i = 0; i < 16; ++i) {
        int e = c * 16 + i;
        int dstE = __float_as_int(stageL[e][13]);
        if (dstE != cur) { flush(cur); acc0 = acc1 = acc2 = 0.f; cur = dstE; }
        float w = Wt[e][part * 64 + lane];
        if (part == 2) {
          float wq = w * stageL[e][8];
          acc0 = fmaf(wq, bA[i], acc0);
          acc1 = fmaf(wq, bB[i], acc1);
          acc2 = fmaf(wq, bC[i], acc2);
        } else {
          float d = fmaf(bA[i], stageL[e][9],
                    fmaf(bB[i], stageL[e][10], bC[i] * stageL[e][11]));
          acc0 = fmaf(w * INV_SQ3, d, acc0);
        }
      }
    };
    loadc(hA, hB, hC, 1);
    proc(gA, gB, gC, 0);
    loadc(gA, gB, gC, 2);
    proc(hA, hB, hC, 1);
    loadc(hA, hB, hC, 3);
    proc(gA, gB, gC, 2);
    proc(hA, hB, hC, 3);
  }
  flush(cur);
}

// ---------------------------------------------------------------------------
// K4: final linear as micro-tiled GEMM, 32 nodes / block, 2x4 register tile.
// ---------------------------------------------------------------------------
__global__ __launch_bounds__(256) void k4_final(
    const float* __restrict__ aggS, const float* __restrict__ aggV,
    const float* __restrict__ W2s, const float* __restrict__ W2v,
    float* __restrict__ out_)
{
  __shared__ float XT[128][33];
  __shared__ float Wl[128][68];
  const int t = threadIdx.x;
  const int n0 = blockIdx.x * 32;
  const int tn = t >> 4, tw = t & 15;

  #pragma unroll
  for (int i = 0; i < 32; ++i) { int idx = t + i * 256; Wl[idx >> 6][idx & 63] = W2s[idx]; }
  #pragma unroll
  for (int i = 0; i < 16; ++i) {
    int idx = t + i * 256;
    int n = idx >> 7, k = idx & 127;
    XT[k][n] = aggS[(size_t)(n0 + n) * 128 + k];
  }
  __syncthreads();
  float acc[2][4] = {{0.f,0.f,0.f,0.f},{0.f,0.f,0.f,0.f}};
  #pragma unroll 8
  for (int kk = 0; kk < 128; ++kk) {
    float a0 = XT[kk][tn * 2 + 0], a1 = XT[kk][tn * 2 + 1];
    float b0 = Wl[kk][tw * 4 + 0], b1 = Wl[kk][tw * 4 + 1];
    float b2 = Wl[kk][tw * 4 + 2], b3 = Wl[kk][tw * 4 + 3];
    acc[0][0] = fmaf(a0, b0, acc[0][0]);
    acc[0][1] = fmaf(a0, b1, acc[0][1]);
    acc[0][2] = fmaf(a0, b2, acc[0][2]);
    acc[0][3] = fmaf(a0, b3, acc[0][3]);
    acc[1][0] = fmaf(a1, b0, acc[1][0]);
    acc[1][1] = fmaf(a1, b1, acc[1][1]);
    acc[1][2] = fmaf(a1, b2, acc[1][2]);
    acc[1][3] = fmaf(a1, b3, acc[1][3]);
  }
  #pragma unroll
  for (int i = 0; i < 2; ++i)
    #pragma unroll
    for (int j = 0; j < 4; ++j)
      out_[(size_t)(n0 + tn * 2 + i) * 256 + tw * 4 + j] += acc[i][j] * AGG_SCALE;

  __syncthreads();
  #pragma unroll
  for (int i = 0; i < 32; ++i) { int idx = t + i * 256; Wl[idx >> 6][idx & 63] = W2v[idx]; }
  float accv[3][2][4];
  #pragma unroll
  for (int c = 0; c < 3; ++c) {
    __syncthreads();
    #pragma unroll
    for (int i = 0; i < 16; ++i) {
      int idx = t + i * 256;
      int n = idx >> 7, k = idx & 127;
      XT[k][n] = aggV[(size_t)(n0 + n) * 384 + c * 128 + k];
    }
    __syncthreads();
    #pragma unroll
    for (int i = 0; i < 2; ++i)
      #pragma unroll
      for (int j = 0; j < 4; ++j) accv[c][i][j] = 0.f;
    #pragma unroll 8
    for (int kk = 0; kk < 128; ++kk) {
      float a0 = XT[kk][tn * 2 + 0], a1 = XT[kk][tn * 2 + 1];
      float b0 = Wl[kk][tw * 4 + 0], b1 = Wl[kk][tw * 4 + 1];
      float b2 = Wl[kk][tw * 4 + 2], b3 = Wl[kk][tw * 4 + 3];
      accv[c][0][0] = fmaf(a0, b0, accv[c][0][0]);
      accv[c][0][1] = fmaf(a0, b1, accv[c][0][1]);
      accv[c][0][2] = fmaf(a0, b2, accv[c][0][2]);
      accv[c][0][3] = fmaf(a0, b3, accv[c][0][3]);
      accv[c][1][0] = fmaf(a1, b0, accv[c][1][0]);
      accv[c][1][1] = fmaf(a1, b1, accv[c][1][1]);
      accv[c][1][2] = fmaf(a1, b2, accv[c][1][2]);
      accv[c][1][3] = fmaf(a1, b3, accv[c][1][3]);
    }
  }
  #pragma unroll
  for (int i = 0; i < 2; ++i) {
    #pragma unroll
    for (int j = 0; j < 4; ++j) {
      size_t base = (size_t)(n0 + tn * 2 + i) * 256 + 64 + (tw * 4 + j) * 3;
      out_[base + 0] += accv[0][i][j] * AGG_SCALE;
      out_[base + 1] += accv[1][i][j] * AGG_SCALE;
      out_[base + 2] += accv[2][i][j] * AGG_SCALE;
    }
  }
}

extern "C" void kernel_launch(void* const* d_in, const int* in_sizes, int n_in,
                              void* d_out, int out_size, void* d_ws, size_t ws_size,
                              hipStream_t stream) {
  const float* node_feat  = (const float*)d_in[0];
  const float* node_attr  = (const float*)d_in[1];
  const float* edge_sh    = (const float*)d_in[2];
  const float* edge_basis = (const float*)d_in[3];
  const float* W1s        = (const float*)d_in[4];
  const float* W1v        = (const float*)d_in[5];
  const float* Wfc1       = (const float*)d_in[6];
  const float* Wfc2       = (const float*)d_in[7];
  const float* W2s        = (const float*)d_in[8];
  const float* W2v        = (const float*)d_in[9];
  const float* Wsc_s      = (const float*)d_in[10];
  const float* Wsc_v      = (const float*)d_in[11];
  const int*   edge_idx   = (const int*)d_in[12];
  float* out = (float*)d_out;

  char* ws = (char*)d_ws;
  float*          ws_s   = (float*)ws;                                   // N*64 f
  float*          ws_v   = (float*)(ws + (size_t)NN * 64 * 4);           // N*192 f
  float*          aggS   = (float*)(ws + (size_t)NN * 256 * 4);          // N*128 f
  float*          aggV   = (float*)(ws + (size_t)NN * 384 * 4);          // N*384 f
  int*            deg    = (int*)  (ws + (size_t)NN * 768 * 4);          // N int
  int*            cursor = (int*)  (ws + (size_t)NN * 769 * 4);          // N int
  unsigned short* wfc2b  = (unsigned short*)(ws + (size_t)NN * 770 * 4); // 16384 u16
  float*          eord   = (float*)(ws + (size_t)NN * 770 * 4 + 32768);  // E*16 f

  hipMemsetAsync(aggS, 0, (size_t)NN * 512 * sizeof(float), stream);
  hipMemsetAsync(deg, 0, (size_t)NN * sizeof(int), stream);

  k_hist        <<<EE / 256, 256, 0, stream>>>(edge_idx, deg);
  k_wprep       <<<64, 256, 0, stream>>>(Wfc2, wfc2b);
  k_scan        <<<1, 1024, 0, stream>>>(deg, cursor);
  k_scatter_pack<<<EE / 256, 256, 0, stream>>>(edge_basis, edge_sh, edge_idx,
                                               cursor, eord);

  k1_node_prep<<<NN / 32, 256, 0, stream>>>(node_feat, node_attr, W1s, W1v,
                                            Wsc_s, Wsc_v, out, ws_s, ws_v);
  k2_edge_csr <<<EE / 64, 256, 0, stream>>>(eord, Wfc1, wfc2b,
                                            ws_s, ws_v, aggS, aggV);
  k4_final    <<<NN / 32, 256, 0, stream>>>(aggS, aggV, W2s, W2v, out);
}

// Round 8
// 400.533 us; speedup vs baseline: 1.3179x; 1.3179x over previous
//
#include <hip/hip_runtime.h>
#include <math.h>

#define NN 20000
#define EE 320000

// scales
#define INV_UV    0.04419417382415922f   // 1/sqrt(64*8)
#define INV_MULS  0.125f                 // 1/sqrt(64)
#define S_BASIS   0.35355339059327373f   // 1/sqrt(8)
#define S_HID     0.125f                 // 1/sqrt(64)
#define INV_SQ3   0.5773502691896258f
#define AGG_SCALE (0.25f * 0.08838834764831845f)  // inv_nn * inv_mid

typedef __attribute__((ext_vector_type(8))) short bf16x8;
typedef __attribute__((ext_vector_type(4))) float f32x4;

__device__ __forceinline__ float sspf(float x) {
  return fmaxf(x, 0.0f) + __logf(1.0f + __expf(-fabsf(x))) - 0.69314718055994531f;
}

__device__ __forceinline__ short f2bf(float f) {
  unsigned u = __float_as_uint(f);
  u += 0x7fffu + ((u >> 16) & 1u);       // round-to-nearest-even
  return (short)(u >> 16);
}

// pack 8 floats -> bf16x8 via f2bf (RNE, same numerics as rest of pipeline)
__device__ __forceinline__ bf16x8 pack8(float f0, float f1, float f2, float f3,
                                        float f4, float f5, float f6, float f7) {
  bf16x8 r;
  r[0] = f2bf(f0); r[1] = f2bf(f1); r[2] = f2bf(f2); r[3] = f2bf(f3);
  r[4] = f2bf(f4); r[5] = f2bf(f5); r[6] = f2bf(f6); r[7] = f2bf(f7);
  return r;
}

// ---------------------------------------------------------------------------
// CSR build: histogram -> single-block scan -> scatter+pack (eord records)
// ---------------------------------------------------------------------------
__global__ __launch_bounds__(256) void k_hist(const int* __restrict__ edge_idx,
                                              int* __restrict__ deg) {
  int e = blockIdx.x * 256 + threadIdx.x;
  atomicAdd(&deg[edge_idx[2 * (size_t)e]], 1);
}

__global__ __launch_bounds__(1024) void k_scan(const int* __restrict__ deg,
                                               int* __restrict__ cursor) {
  __shared__ int part[1024];
  const int t = threadIdx.x;
  const int base = t * 20;
  int loc[20];
  int run = 0;
  #pragma unroll
  for (int i = 0; i < 20; ++i) {
    int idx = base + i;
    int v = (idx < NN) ? deg[idx] : 0;
    loc[i] = run; run += v;
  }
  part[t] = run;
  __syncthreads();
  for (int off = 1; off < 1024; off <<= 1) {
    int v = (t >= off) ? part[t - off] : 0;
    __syncthreads();
    part[t] += v;
    __syncthreads();
  }
  int ex = (t > 0) ? part[t - 1] : 0;
  #pragma unroll
  for (int i = 0; i < 20; ++i) {
    int idx = base + i;
    if (idx < NN) cursor[idx] = ex + loc[i];
  }
}

__global__ __launch_bounds__(256) void k_scatter_pack(
    const float* __restrict__ edge_basis, const float* __restrict__ edge_sh,
    const int* __restrict__ edge_idx, int* __restrict__ cursor,
    float* __restrict__ eord) {
  int e = blockIdx.x * 256 + threadIdx.x;
  int2 di = *(const int2*)(edge_idx + 2 * (size_t)e);
  int pos = atomicAdd(&cursor[di.x], 1);
  float4 b0 = *(const float4*)(edge_basis + (size_t)e * 8);
  float4 b1 = *(const float4*)(edge_basis + (size_t)e * 8 + 4);
  float4 s4 = *(const float4*)(edge_sh + (size_t)e * 4);
  float* r = eord + (size_t)pos * 16;
  *(float4*)(r)     = b0;
  *(float4*)(r + 4) = b1;
  *(float4*)(r + 8) = s4;
  r[12] = __int_as_float(di.y);   // src
  r[13] = __int_as_float(di.x);   // dst
}

// ---------------------------------------------------------------------------
// k_prep: all weight preconversions to bf16.
//  buf segments (u16 elems):
//   [0,16384)        wfc2b   (fragment order, S_HID folded)
//   [16384,49152)    WscT_s  [w][k=512]
//   [49152,81920)    WscT_v  [w][k=512]
//   [81920,86016)    W1T_s   [w][k=64]
//   [86016,90112)    W1T_v   [w][k=64]
//   [90112,98304)    W2T_s   [w][k=128]
//   [98304,106496)   W2T_v   [w][k=128]
// ---------------------------------------------------------------------------
__global__ __launch_bounds__(256) void k_prep(
    const float* __restrict__ Wfc2,
    const float* __restrict__ Wsc_s, const float* __restrict__ Wsc_v,
    const float* __restrict__ W1s, const float* __restrict__ W1v,
    const float* __restrict__ W2s, const float* __restrict__ W2v,
    unsigned short* __restrict__ buf) {
  int i = blockIdx.x * 256 + threadIdx.x;   // grid 416 -> 106496 exact
  float val;
  if (i < 16384) {
    int tt = i >> 6;
    int ks = (i >> 5) & 1;
    int nt = (i >> 3) & 3;
    int j  = i & 7;
    int lane = tt & 63, wvv = tt >> 6;
    int row = ks * 32 + (lane >> 4) * 8 + j;
    int col = wvv * 64 + nt * 16 + (lane & 15);
    val = Wfc2[(size_t)row * 256 + col] * S_HID;
  } else if (i < 49152) {
    int j = i - 16384; int w = j >> 9, k = j & 511;
    val = Wsc_s[(size_t)k * 64 + w];
  } else if (i < 81920) {
    int j = i - 49152; int w = j >> 9, k = j & 511;
    val = Wsc_v[(size_t)k * 64 + w];
  } else if (i < 86016) {
    int j = i - 81920; int w = j >> 6, k = j & 63;
    val = W1s[(size_t)k * 64 + w];
  } else if (i < 90112) {
    int j = i - 86016; int w = j >> 6, k = j & 63;
    val = W1v[(size_t)k * 64 + w];
  } else if (i < 98304) {
    int j = i - 90112; int w = j >> 7, k = j & 127;
    val = W2s[(size_t)k * 64 + w];
  } else {
    int j = i - 98304; int w = j >> 7, k = j & 127;
    val = W2v[(size_t)k * 64 + w];
  }
  buf[i] = (unsigned short)f2bf(val);
}

// ---------------------------------------------------------------------------
// K1 (MFMA): 32 nodes / block, 4 waves; wave ch = channel (s, vx, vy, vz).
//  sc:  X(32x512) @ WscT-chunks, A built on the fly (S[n][u]*attr[n][v]).
//  lin1: S(32x64) @ W1T.  B-fragments straight from global bf16 (L1/L2-hot).
//  One barrier total (after SL staging).
// ---------------------------------------------------------------------------
__global__ __launch_bounds__(256) void k1_node_prep(
    const float* __restrict__ node_feat, const float* __restrict__ node_attr,
    const unsigned short* __restrict__ wscT_s, const unsigned short* __restrict__ wscT_v,
    const unsigned short* __restrict__ w1T_s, const unsigned short* __restrict__ w1T_v,
    float* __restrict__ out_, float* __restrict__ ws_s, float* __restrict__ ws_v)
{
  __shared__ float SL[4][32][68];    // [ch][node][u]; ch0=s0, 1..3=v_c. 34.8 KB
  __shared__ float attrL[32][8];

  const int t = threadIdx.x;
  const int n0 = blockIdx.x * 32;
  const int ch = t >> 6, lane = t & 63;
  const int er = lane & 15, hi = lane >> 4;

  // stage node_feat (32 x 256 f32) split into SL channels
  const float4* nf4 = (const float4*)(node_feat + (size_t)n0 * 256);
  #pragma unroll
  for (int i = 0; i < 8; ++i) {
    int idx = t + i * 256;          // 0..2047
    int n = idx >> 6, j4 = idx & 63;
    float4 v = nf4[idx];
    #pragma unroll
    for (int r = 0; r < 4; ++r) {
      int col = j4 * 4 + r;
      float f = (&v.x)[r];
      if (col < 64) SL[0][n][col] = f;
      else { int cc = col - 64; SL[1 + cc % 3][n][cc / 3] = f; }
    }
  }
  attrL[t >> 3][t & 7] = node_attr[(size_t)(n0 + (t >> 3)) * 8 + (t & 7)];
  __syncthreads();

  const float (*S)[68] = SL[ch];
  const unsigned short* scT = (ch == 0) ? wscT_s : wscT_v;
  const unsigned short* l1T = (ch == 0) ? w1T_s : w1T_v;

  float attrR[2][8];
  #pragma unroll
  for (int mt = 0; mt < 2; ++mt)
    #pragma unroll
    for (int j = 0; j < 8; ++j)
      attrR[mt][j] = attrL[mt * 16 + er][j];

  // ---- self-connection: (32 x 512) @ (512 x 64), K-chunks of 64 ----
  f32x4 acc[2][4];
  #pragma unroll
  for (int mt = 0; mt < 2; ++mt)
    #pragma unroll
    for (int nt = 0; nt < 4; ++nt)
      acc[mt][nt] = (f32x4){0.f, 0.f, 0.f, 0.f};

  bf16x8 bc[8], bn[8];
  #pragma unroll
  for (int kt = 0; kt < 2; ++kt)
    #pragma unroll
    for (int nt = 0; nt < 4; ++nt)
      bc[kt * 4 + nt] = *(const bf16x8*)(scT + (size_t)(nt * 16 + er) * 512 + kt * 32 + hi * 8);

  #pragma unroll
  for (int kc = 0; kc < 8; ++kc) {
    if (kc < 7) {
      #pragma unroll
      for (int kt = 0; kt < 2; ++kt)
        #pragma unroll
        for (int nt = 0; nt < 4; ++nt)
          bn[kt * 4 + nt] = *(const bf16x8*)(scT + (size_t)(nt * 16 + er) * 512 +
                                             (kc + 1) * 64 + kt * 32 + hi * 8);
    }
    #pragma unroll
    for (int kt = 0; kt < 2; ++kt) {
      bf16x8 a[2];
      #pragma unroll
      for (int mt = 0; mt < 2; ++mt) {
        float su = S[mt * 16 + er][kc * 8 + kt * 4 + hi];
        a[mt] = pack8(su * attrR[mt][0], su * attrR[mt][1], su * attrR[mt][2], su * attrR[mt][3],
                      su * attrR[mt][4], su * attrR[mt][5], su * attrR[mt][6], su * attrR[mt][7]);
      }
      #pragma unroll
      for (int nt = 0; nt < 4; ++nt) {
        acc[0][nt] = __builtin_amdgcn_mfma_f32_16x16x32_bf16(a[0], bc[kt * 4 + nt], acc[0][nt], 0, 0, 0);
        acc[1][nt] = __builtin_amdgcn_mfma_f32_16x16x32_bf16(a[1], bc[kt * 4 + nt], acc[1][nt], 0, 0, 0);
      }
    }
    #pragma unroll
    for (int q = 0; q < 8; ++q) bc[q] = bn[q];
  }
  // sc epilogue: write out (full coverage, '=' stores)
  #pragma unroll
  for (int mt = 0; mt < 2; ++mt)
    #pragma unroll
    for (int nt = 0; nt < 4; ++nt)
      #pragma unroll
      for (int r = 0; r < 4; ++r) {
        int node = n0 + mt * 16 + hi * 4 + r;
        int w = nt * 16 + er;
        float val = acc[mt][nt][r] * INV_UV;
        if (ch == 0) out_[(size_t)node * 256 + w] = val;
        else         out_[(size_t)node * 256 + 64 + w * 3 + (ch - 1)] = val;
      }

  // ---- linear1: (32 x 64) @ (64 x 64) ----
  f32x4 acc1[2][4];
  #pragma unroll
  for (int mt = 0; mt < 2; ++mt)
    #pragma unroll
    for (int nt = 0; nt < 4; ++nt)
      acc1[mt][nt] = (f32x4){0.f, 0.f, 0.f, 0.f};

  #pragma unroll
  for (int kt = 0; kt < 2; ++kt) {
    bf16x8 a[2];
    #pragma unroll
    for (int mt = 0; mt < 2; ++mt) {
      const float* sp = &S[mt * 16 + er][kt * 32 + hi * 8];
      float4 p0 = *(const float4*)sp;
      float4 p1 = *(const float4*)(sp + 4);
      a[mt] = pack8(p0.x, p0.y, p0.z, p0.w, p1.x, p1.y, p1.z, p1.w);
    }
    #pragma unroll
    for (int nt = 0; nt < 4; ++nt) {
      bf16x8 b = *(const bf16x8*)(l1T + (size_t)(nt * 16 + er) * 64 + kt * 32 + hi * 8);
      acc1[0][nt] = __builtin_amdgcn_mfma_f32_16x16x32_bf16(a[0], b, acc1[0][nt], 0, 0, 0);
      acc1[1][nt] = __builtin_amdgcn_mfma_f32_16x16x32_bf16(a[1], b, acc1[1][nt], 0, 0, 0);
    }
  }
  #pragma unroll
  for (int mt = 0; mt < 2; ++mt)
    #pragma unroll
    for (int nt = 0; nt < 4; ++nt)
      #pragma unroll
      for (int r = 0; r < 4; ++r) {
        int node = n0 + mt * 16 + hi * 4 + r;
        int w = nt * 16 + er;
        float val = acc1[mt][nt][r] * INV_MULS;
        if (ch == 0) ws_s[(size_t)node * 64 + w] = val;
        else         ws_v[((size_t)node * 3 + (ch - 1)) * 64 + w] = val;
      }
}

// ---------------------------------------------------------------------------
// K2: 64 dst-sorted edges / block; bf16 Wt (LDS 80->47 KB, 3 blocks/CU).
// ---------------------------------------------------------------------------
__global__ __launch_bounds__(256) void k2_edge_csr(
    const float* __restrict__ eord, const float* __restrict__ Wfc1,
    const unsigned short* __restrict__ wfc2b,
    const float* __restrict__ ws_s, const float* __restrict__ ws_v,
    float* __restrict__ aggS, float* __restrict__ aggV)
{
  __shared__ float stageL[64][16];
  __shared__ float wfc1[8][64];
  __shared__ short Hlb[64 * 64];             // bf16 H, XOR-swizzled (8 KB)
  __shared__ unsigned short Wtb[64][264];    // bf16 W (33 KB)

  const int t = threadIdx.x;
  const int e0 = blockIdx.x * 64;
  const int wv = t >> 6, lane = t & 63;

  {
    float4 r = *(const float4*)(eord + (size_t)e0 * 16 + t * 4);
    *(float4*)&stageL[t >> 2][(t & 3) * 4] = r;
  }
  #pragma unroll
  for (int i = 0; i < 2; ++i) {
    int idx = t + i * 256;
    wfc1[idx >> 6][idx & 63] = Wfc1[idx] * S_BASIS;
  }
  bf16x8 bfrag[2][4];
  {
    const bf16x8* p = (const bf16x8*)(wfc2b + (size_t)t * 64);
    #pragma unroll
    for (int ks = 0; ks < 2; ++ks)
      #pragma unroll
      for (int nt = 0; nt < 4; ++nt)
        bfrag[ks][nt] = p[ks * 4 + nt];
  }
  __syncthreads();

  // preload gather chunk 0
  float gA[16], gB[16], gC[16];
  #pragma unroll
  for (int i = 0; i < 16; ++i) {
    int s = __float_as_int(stageL[i][12]);
    if (wv <= 1) gA[i] = ws_s[(size_t)s * 64 + lane];
    else {
      const float* p = ws_v + (size_t)s * 192 + lane;
      gA[i] = p[0]; gB[i] = p[64]; gC[i] = p[128];
    }
  }

  // H = ssp(basis @ wfc1) -> bf16 swizzled LDS
  #pragma unroll
  for (int i = 0; i < 8; ++i) {
    int idx = t + i * 256;
    int e = idx >> 5, j2 = idx & 31;
    float a0 = 0.f, a1 = 0.f;
    #pragma unroll
    for (int b = 0; b < 8; ++b) {
      float bs = stageL[e][b];
      a0 = fmaf(bs, wfc1[b][2 * j2 + 0], a0);
      a1 = fmaf(bs, wfc1[b][2 * j2 + 1], a1);
    }
    unsigned pck = ((unsigned)(unsigned short)f2bf(sspf(a0))) |
                   (((unsigned)(unsigned short)f2bf(sspf(a1))) << 16);
    int byte_off = e * 128 + ((j2 * 4) ^ ((e & 7) << 4));
    *(unsigned*)((char*)Hlb + byte_off) = pck;
  }
  __syncthreads();

  // MFMA: Wt = H @ Wfc2
  {
    const int er = lane & 15;
    const int kr = (lane >> 4) * 8;
    #pragma unroll
    for (int mt = 0; mt < 4; ++mt) {
      int e = mt * 16 + er;
      bf16x8 af0 = *(const bf16x8*)((const char*)Hlb + e * 128 + ((kr * 2)        ^ ((e & 7) << 4)));
      bf16x8 af1 = *(const bf16x8*)((const char*)Hlb + e * 128 + (((32 + kr) * 2) ^ ((e & 7) << 4)));
      #pragma unroll
      for (int nt = 0; nt < 4; ++nt) {
        f32x4 acc = {0.f, 0.f, 0.f, 0.f};
        acc = __builtin_amdgcn_mfma_f32_16x16x32_bf16(af0, bfrag[0][nt], acc, 0, 0, 0);
        acc = __builtin_amdgcn_mfma_f32_16x16x32_bf16(af1, bfrag[1][nt], acc, 0, 0, 0);
        int row = mt * 16 + (lane >> 4) * 4;
        int col = wv * 64 + nt * 16 + (lane & 15);
        #pragma unroll
        for (int r = 0; r < 4; ++r)
          Wtb[row + r][col] = (unsigned short)f2bf(acc[r]);
      }
    }
  }
  __syncthreads();

  // TP: 4 chunks of 16, double-buffered gathers, flush on dst change
  const int part = wv;
  float acc0 = 0.f, acc1 = 0.f, acc2 = 0.f;
  int cur = __float_as_int(stageL[0][13]);

  auto flush = [&](int node) {
    size_t nb = (size_t)node;
    if (part == 0)      atomicAdd(&aggS[nb * 128 + lane], acc0);
    else if (part == 3) atomicAdd(&aggS[nb * 128 + 64 + lane], acc0);
    else if (part == 1) {
      atomicAdd(&aggV[nb * 384 +       lane], acc0);
      atomicAdd(&aggV[nb * 384 + 128 + lane], acc1);
      atomicAdd(&aggV[nb * 384 + 256 + lane], acc2);
    } else {
      atomicAdd(&aggV[nb * 384 +  64 + lane], acc0);
      atomicAdd(&aggV[nb * 384 + 192 + lane], acc1);
      atomicAdd(&aggV[nb * 384 + 320 + lane], acc2);
    }
  };
  auto rdw = [&](int e) -> float {
    return __uint_as_float(((unsigned)Wtb[e][part * 64 + lane]) << 16);
  };

  if (part <= 1) {
    float hA[16];
    auto loadc = [&](float* bA, int c) {
      #pragma unroll
      for (int i = 0; i < 16; ++i) {
        int s = __float_as_int(stageL[c * 16 + i][12]);
        bA[i] = ws_s[(size_t)s * 64 + lane];
      }
    };
    auto proc = [&](const float* bA, int c) {
      #pragma unroll
      for (int i = 0; i < 16; ++i) {
        int e = c * 16 + i;
        int dstE = __float_as_int(stageL[e][13]);
        if (dstE != cur) { flush(cur); acc0 = acc1 = acc2 = 0.f; cur = dstE; }
        float w = rdw(e);
        if (part == 0) {
          acc0 = fmaf(w * bA[i], stageL[e][8], acc0);
        } else {
          float wx = w * bA[i];
          acc0 = fmaf(wx, stageL[e][9],  acc0);
          acc1 = fmaf(wx, stageL[e][10], acc1);
          acc2 = fmaf(wx, stageL[e][11], acc2);
        }
      }
    };
    loadc(hA, 1);
    proc(gA, 0);
    loadc(gA, 2);
    proc(hA, 1);
    loadc(hA, 3);
    proc(gA, 2);
    proc(hA, 3);
  } else {
    float hA[16], hB[16], hC[16];
    auto loadc = [&](float* bA, float* bB, float* bC, int c) {
      #pragma unroll
      for (int i = 0; i < 16; ++i) {
        int s = __float_as_int(stageL[c * 16 + i][12]);
        const float* p = ws_v + (size_t)s * 192 + lane;
        bA[i] = p[0]; bB[i] = p[64]; bC[i] = p[128];
      }
    };
    auto proc = [&](const float* bA, const float* bB, const float* bC, int c) {
      #pragma unroll
      for (int i = 0; i < 16; ++i) {
        int e = c * 16 + i;
        int dstE = __float_as_int(stageL[e][13]);
        if (dstE != cur) { flush(cur); acc0 = acc1 = acc2 = 0.f; cur = dstE; }
        float w = rdw(e);
        if (part == 2) {
          float wq = w * stageL[e][8];
          acc0 = fmaf(wq, bA[i], acc0);
          acc1 = fmaf(wq, bB[i], acc1);
          acc2 = fmaf(wq, bC[i], acc2);
        } else {
          float d = fmaf(bA[i], stageL[e][9],
                    fmaf(bB[i], stageL[e][10], bC[i] * stageL[e][11]));
          acc0 = fmaf(w * INV_SQ3, d, acc0);
        }
      }
    };
    loadc(hA, hB, hC, 1);
    proc(gA, gB, gC, 0);
    loadc(gA, gB, gC, 2);
    proc(hA, hB, hC, 1);
    loadc(hA, hB, hC, 3);
    proc(gA, gB, gC, 2);
    proc(hA, hB, hC, 3);
  }
  flush(cur);
}

// ---------------------------------------------------------------------------
// K4 (MFMA, no LDS): 32 nodes / block, wave ch = channel.
//  out += (agg @ W2) * AGG_SCALE ; A from global agg, B from W2T bf16.
// ---------------------------------------------------------------------------
__global__ __launch_bounds__(256) void k4_final(
    const float* __restrict__ aggS, const float* __restrict__ aggV,
    const unsigned short* __restrict__ w2T_s, const unsigned short* __restrict__ w2T_v,
    float* __restrict__ out_)
{
  const int t = threadIdx.x;
  const int n0 = blockIdx.x * 32;
  const int ch = t >> 6, lane = t & 63;
  const int er = lane & 15, hi = lane >> 4;
  const unsigned short* BT = (ch == 0) ? w2T_s : w2T_v;

  f32x4 acc[2][4];
  #pragma unroll
  for (int mt = 0; mt < 2; ++mt)
    #pragma unroll
    for (int nt = 0; nt < 4; ++nt)
      acc[mt][nt] = (f32x4){0.f, 0.f, 0.f, 0.f};

  #pragma unroll
  for (int kt = 0; kt < 4; ++kt) {
    bf16x8 a[2];
    #pragma unroll
    for (int mt = 0; mt < 2; ++mt) {
      int node = n0 + mt * 16 + er;
      const float* Ap = (ch == 0)
          ? (aggS + (size_t)node * 128 + kt * 32 + hi * 8)
          : (aggV + (size_t)node * 384 + (ch - 1) * 128 + kt * 32 + hi * 8);
      float4 p0 = *(const float4*)Ap;
      float4 p1 = *(const float4*)(Ap + 4);
      a[mt] = pack8(p0.x, p0.y, p0.z, p0.w, p1.x, p1.y, p1.z, p1.w);
    }
    #pragma unroll
    for (int nt = 0; nt < 4; ++nt) {
      bf16x8 b = *(const bf16x8*)(BT + (size_t)(nt * 16 + er) * 128 + kt * 32 + hi * 8);
      acc[0][nt] = __builtin_amdgcn_mfma_f32_16x16x32_bf16(a[0], b, acc[0][nt], 0, 0, 0);
      acc[1][nt] = __builtin_amdgcn_mfma_f32_16x16x32_bf16(a[1], b, acc[1][nt], 0, 0, 0);
    }
  }
  #pragma unroll
  for (int mt = 0; mt < 2; ++mt)
    #pragma unroll
    for (int nt = 0; nt < 4; ++nt)
      #pragma unroll
      for (int r = 0; r < 4; ++r) {
        int node = n0 + mt * 16 + hi * 4 + r;
        int w = nt * 16 + er;
        size_t o = (ch == 0) ? (size_t)node * 256 + w
                             : (size_t)node * 256 + 64 + w * 3 + (ch - 1);
        out_[o] += acc[mt][nt][r] * AGG_SCALE;
      }
}

extern "C" void kernel_launch(void* const* d_in, const int* in_sizes, int n_in,
                              void* d_out, int out_size, void* d_ws, size_t ws_size,
                              hipStream_t stream) {
  const float* node_feat  = (const float*)d_in[0];
  const float* node_attr  = (const float*)d_in[1];
  const float* edge_sh    = (const float*)d_in[2];
  const float* edge_basis = (const float*)d_in[3];
  const float* W1s        = (const float*)d_in[4];
  const float* W1v        = (const float*)d_in[5];
  const float* Wfc1       = (const float*)d_in[6];
  const float* Wfc2       = (const float*)d_in[7];
  const float* W2s        = (const float*)d_in[8];
  const float* W2v        = (const float*)d_in[9];
  const float* Wsc_s      = (const float*)d_in[10];
  const float* Wsc_v      = (const float*)d_in[11];
  const int*   edge_idx   = (const int*)d_in[12];
  float* out = (float*)d_out;

  char* ws = (char*)d_ws;
  float*          ws_s   = (float*)ws;                                   // N*64 f
  float*          ws_v   = (float*)(ws + (size_t)NN * 64 * 4);           // N*192 f
  float*          aggS   = (float*)(ws + (size_t)NN * 256 * 4);          // N*128 f
  float*          aggV   = (float*)(ws + (size_t)NN * 384 * 4);          // N*384 f
  int*            deg    = (int*)  (ws + (size_t)NN * 768 * 4);          // N int
  int*            cursor = (int*)  (ws + (size_t)NN * 769 * 4);          // N int
  unsigned short* buf    = (unsigned short*)(ws + (size_t)NN * 770 * 4); // 106496 u16
  float*          eord   = (float*)(ws + (size_t)NN * 770 * 4 + 212992); // E*16 f

  unsigned short* wfc2b  = buf;
  unsigned short* wscT_s = buf + 16384;
  unsigned short* wscT_v = buf + 49152;
  unsigned short* w1T_s  = buf + 81920;
  unsigned short* w1T_v  = buf + 86016;
  unsigned short* w2T_s  = buf + 90112;
  unsigned short* w2T_v  = buf + 98304;

  hipMemsetAsync(aggS, 0, (size_t)NN * 512 * sizeof(float), stream);
  hipMemsetAsync(deg, 0, (size_t)NN * sizeof(int), stream);

  k_hist        <<<EE / 256, 256, 0, stream>>>(edge_idx, deg);
  k_prep        <<<416, 256, 0, stream>>>(Wfc2, Wsc_s, Wsc_v, W1s, W1v, W2s, W2v, buf);
  k_scan        <<<1, 1024, 0, stream>>>(deg, cursor);
  k_scatter_pack<<<EE / 256, 256, 0, stream>>>(edge_basis, edge_sh, edge_idx,
                                               cursor, eord);

  k1_node_prep<<<NN / 32, 256, 0, stream>>>(node_feat, node_attr,
                                            wscT_s, wscT_v, w1T_s, w1T_v,
                                            out, ws_s, ws_v);
  k2_edge_csr <<<EE / 64, 256, 0, stream>>>(eord, Wfc1, wfc2b,
                                            ws_s, ws_v, aggS, aggV);
  k4_final    <<<NN / 32, 256, 0, stream>>>(aggS, aggV, w2T_s, w2T_v, out);
}